// Round 1
// baseline (954.512 us; speedup 1.0000x reference)
//
#include <hip/hip_runtime.h>
#include <cstdint>
#include <cstddef>

// Problem constants
#define OBS_DIMM 128
#define PROJJ    64
#define HIDD     256
#define LATT     24
#define BBATCH   1024
#define TTIME    256
#define KDIM     384   // 128 obs-cols + 256 h-cols
#define NGATE    768   // 3*HID
#define MBLK     32    // batches per block
#define CHUNK    32    // timesteps per block
#define XSTRIDE  392   // 384 + 8 pad (bf16 elems) -> 196 words, +4 mod 32 bank skew
#define MSTRIDE  264   // 256 + 8 pad

using bf16x8 = __attribute__((ext_vector_type(8))) short;   // 8 bf16 in 4 VGPRs
using f32x4  = __attribute__((ext_vector_type(4))) float;

static __device__ __forceinline__ unsigned short f2bf(float f) {
    unsigned u = __builtin_bit_cast(unsigned, f);
    u += 0x7fffu + ((u >> 16) & 1u);          // RNE
    return (unsigned short)(u >> 16);
}
static __device__ __forceinline__ float bf2f(unsigned short h) {
    return __builtin_bit_cast(float, ((unsigned)h) << 16);
}
static __device__ __forceinline__ float fexp2(float x) { return __builtin_amdgcn_exp2f(x); }
static __device__ __forceinline__ float flog2(float x) { return __builtin_amdgcn_logf(x); }
static __device__ __forceinline__ float frcp (float x) { return __builtin_amdgcn_rcpf(x); }
static __device__ __forceinline__ float sigmoid_(float x) { return frcp(1.f + fexp2(-1.44269504f * x)); }
static __device__ __forceinline__ float tanh_(float x)    { return 1.f - 2.f * frcp(fexp2(2.88539008f * x) + 1.f); }

#define MFMA16(a, b, c) __builtin_amdgcn_mfma_f32_16x16x32_bf16((a), (b), (c), 0, 0, 0)

// ---------------------------------------------------------------------------
// Prep: build bf16-swizzled fused weight W' = [[W_in@W_ih],[W_hh]] (384x768),
// swizzled W_out (256x32, cols>=24 zero), and b_x = b_in@W_ih + b_ih.
// Swizzle puts each MFMA B-fragment's per-lane 8 bf16 contiguous, wave-coalesced.
// ---------------------------------------------------------------------------
__global__ void prep_kernel(const float* __restrict__ W_in, const float* __restrict__ b_in,
                            const float* __restrict__ W_ih, const float* __restrict__ b_ih,
                            const float* __restrict__ W_hh, const float* __restrict__ W_out,
                            unsigned short* __restrict__ wsW, unsigned short* __restrict__ wsWo,
                            float* __restrict__ wsBx) {
    int idx = blockIdx.x * 256 + threadIdx.x;
    if (idx < KDIM * NGATE) {
        int k = idx / NGATE, n = idx - k * NGATE;
        float s;
        if (k < OBS_DIMM) {
            s = 0.f;
            for (int j = 0; j < PROJJ; ++j) s += W_in[k * PROJJ + j] * W_ih[j * NGATE + n];
        } else {
            s = W_hh[(k - OBS_DIMM) * NGATE + n];
        }
        int nt = n >> 4, nl = n & 15, ks = k >> 5, q = (k >> 3) & 3, jj = k & 7;
        wsW[(nt * 12 + ks) * 512 + (q * 16 + nl) * 8 + jj] = f2bf(s);
    } else if (idx < KDIM * NGATE + 256 * 32) {
        int i2 = idx - KDIM * NGATE;
        int k = i2 >> 5, n = i2 & 31;
        float s = (n < LATT) ? W_out[k * LATT + n] : 0.f;
        int nt = n >> 4, nl = n & 15, ks = k >> 5, q = (k >> 3) & 3, jj = k & 7;
        wsWo[(nt * 8 + ks) * 512 + (q * 16 + nl) * 8 + jj] = f2bf(s);
    } else if (idx < KDIM * NGATE + 256 * 32 + NGATE) {
        int n = idx - (KDIM * NGATE + 256 * 32);
        float s = b_ih[n];
        for (int j = 0; j < PROJJ; ++j) s += b_in[j] * W_ih[j * NGATE + n];
        wsBx[n] = s;
    }
}

// ---------------------------------------------------------------------------
// Main: grid = 32 batch-groups x 8 time-chunks. Each block backtracks to the
// most recent episode reset (h==0 there), rolls the GRU forward, fuses the
// mish + W_out epilogue, and writes out[] only for its own chunk.
// 8 waves: wave w owns hidden units [32w,32w+32) -> gate n-tiles
// {2w,2w+1}+{0,16,32}: r/z/n land in the same lane/reg -> wave-local gates.
// ---------------------------------------------------------------------------
__global__ __launch_bounds__(512, 2)
void gru_kernel(const float* __restrict__ obs, const int* __restrict__ is_init,
                const float* __restrict__ hx, const float* __restrict__ b_hh,
                const float* __restrict__ b_out,
                const unsigned short* __restrict__ wsW, const unsigned short* __restrict__ wsWo,
                const float* __restrict__ wsBx,
                float* __restrict__ out, float* __restrict__ hfin) {
    __shared__ __align__(16) unsigned short sX[MBLK * XSTRIDE];  // [obs_t bf16 | h bf16]
    __shared__ __align__(16) unsigned short sM[MBLK * MSTRIDE];  // mish(h_new) bf16
    __shared__ int sT;

    const int tid  = threadIdx.x;
    const int w    = tid >> 6;
    const int lane = tid & 63;
    const int q    = lane >> 4;
    const int c16  = lane & 15;
    const int bid  = blockIdx.x;
    const int g    = bid & 31;
    const int ch   = bid >> 5;
    const int b0   = g * MBLK;
    const int t0   = ch * CHUNK;

    // per-wave biases (col = (2w+i)*16 + c16)
    float bR[2], bZ[2], bXN[2], bHN[2];
#pragma unroll
    for (int i = 0; i < 2; ++i) {
        int u = (2 * w + i) * 16 + c16;
        bR[i]  = wsBx[u] + b_hh[u];
        bZ[i]  = wsBx[HIDD + u] + b_hh[HIDD + u];
        bXN[i] = wsBx[2 * HIDD + u];
        bHN[i] = b_hh[2 * HIDD + u];
    }

    // resident W_out fragments (waves 0..3 do the epilogue GEMM)
    bf16x8 wo[8];
    float bOutV = 0.f;
    if (w < 4) {
        int nto = w & 1;
#pragma unroll
        for (int ks = 0; ks < 8; ++ks)
            wo[ks] = *(const bf16x8*)(wsWo + (nto * 8 + ks) * 512 + lane * 8);
        int col = nto * 16 + c16;
        bOutV = (col < LATT) ? b_out[col] : 0.f;
    }

    // ---- find start time: most recent reset before t0 (min over group) ----
    if (tid == 0) sT = (ch == 0) ? 0 : 0x7fffffff;
    __syncthreads();
    if (ch > 0 && tid < MBLK) {
        int b = b0 + tid, fs = 0;
        for (int t = t0 - 1; t > 0; --t) {
            if (is_init[b * TTIME + t] != 0) { fs = t; break; }
        }
        atomicMin(&sT, fs);
    }
    __syncthreads();
    const int tstart = sT;

    // ---- init hidden part of X: hx if starting at t=0 (hx==correct h_-1), else 0
    {
        int bl = tid >> 4, part = tid & 15;
        bf16x8 v0 = {0, 0, 0, 0, 0, 0, 0, 0}, v1 = {0, 0, 0, 0, 0, 0, 0, 0};
        if (tstart == 0) {
            const float* hp = hx + (size_t)(b0 + bl) * HIDD + part * 16;
#pragma unroll
            for (int ii = 0; ii < 8; ++ii) {
                v0[ii] = (short)f2bf(hp[ii]);
                v1[ii] = (short)f2bf(hp[8 + ii]);
            }
        }
        *(bf16x8*)(sX + bl * XSTRIDE + OBS_DIMM + part * 16)     = v0;
        *(bf16x8*)(sX + bl * XSTRIDE + OBS_DIMM + part * 16 + 8) = v1;
    }
    __syncthreads();

    const unsigned short* wpl = wsW + lane * 8;
    const int tend = t0 + CHUNK;

    for (int t = tstart; t < tend; ++t) {
        // ---- phase 1: stage obs_t (bf16) into X cols [0,128); apply reset mask to h cols
        {
            int bl = tid >> 4, part = tid & 15;
            const float* op = obs + ((size_t)((b0 + bl) * TTIME + t)) * OBS_DIMM + part * 8;
            float4 a = *(const float4*)op;
            float4 b = *(const float4*)(op + 4);
            bf16x8 pk;
            pk[0] = (short)f2bf(a.x); pk[1] = (short)f2bf(a.y);
            pk[2] = (short)f2bf(a.z); pk[3] = (short)f2bf(a.w);
            pk[4] = (short)f2bf(b.x); pk[5] = (short)f2bf(b.y);
            pk[6] = (short)f2bf(b.z); pk[7] = (short)f2bf(b.w);
            *(bf16x8*)(sX + bl * XSTRIDE + part * 8) = pk;
            if (is_init[(b0 + bl) * TTIME + t] != 0) {
                bf16x8 z8 = {0, 0, 0, 0, 0, 0, 0, 0};
                *(bf16x8*)(sX + bl * XSTRIDE + OBS_DIMM + part * 16)     = z8;
                *(bf16x8*)(sX + bl * XSTRIDE + OBS_DIMM + part * 16 + 8) = z8;
            }
        }
        __syncthreads();

        // ---- phase 2: gates[32,768] = [obs|h] @ W'  (K=384), n-gate split at k=128
        f32x4 accR[2][2], accZ[2][2], accXN[2][2], accHN[2][2];
#pragma unroll
        for (int mt = 0; mt < 2; ++mt)
#pragma unroll
            for (int i = 0; i < 2; ++i) {
                accR[mt][i]  = (f32x4){bR[i], bR[i], bR[i], bR[i]};
                accZ[mt][i]  = (f32x4){bZ[i], bZ[i], bZ[i], bZ[i]};
                accXN[mt][i] = (f32x4){bXN[i], bXN[i], bXN[i], bXN[i]};
                accHN[mt][i] = (f32x4){bHN[i], bHN[i], bHN[i], bHN[i]};
            }
        for (int ks = 0; ks < 12; ++ks) {
            bf16x8 a0 = *(const bf16x8*)(sX + c16 * XSTRIDE + ks * 32 + q * 8);
            bf16x8 a1 = *(const bf16x8*)(sX + (16 + c16) * XSTRIDE + ks * 32 + q * 8);
#pragma unroll
            for (int i = 0; i < 2; ++i) {
                int base = 2 * w + i;
                bf16x8 fR = *(const bf16x8*)(wpl + ((size_t)(base * 12 + ks)) * 512);
                bf16x8 fZ = *(const bf16x8*)(wpl + ((size_t)((16 + base) * 12 + ks)) * 512);
                bf16x8 fN = *(const bf16x8*)(wpl + ((size_t)((32 + base) * 12 + ks)) * 512);
                accR[0][i] = MFMA16(a0, fR, accR[0][i]);
                accR[1][i] = MFMA16(a1, fR, accR[1][i]);
                accZ[0][i] = MFMA16(a0, fZ, accZ[0][i]);
                accZ[1][i] = MFMA16(a1, fZ, accZ[1][i]);
                if (ks < 4) {  // obs half of n-gate
                    accXN[0][i] = MFMA16(a0, fN, accXN[0][i]);
                    accXN[1][i] = MFMA16(a1, fN, accXN[1][i]);
                } else {       // h half of n-gate
                    accHN[0][i] = MFMA16(a0, fN, accHN[0][i]);
                    accHN[1][i] = MFMA16(a1, fN, accHN[1][i]);
                }
            }
        }
        __syncthreads();  // all A-frag reads of X done before h is overwritten

        // ---- phase 3: wave-local gate nonlinearity + h update + mish
#pragma unroll
        for (int mt = 0; mt < 2; ++mt)
#pragma unroll
            for (int i = 0; i < 2; ++i) {
                int u = (2 * w + i) * 16 + c16;
#pragma unroll
                for (int r = 0; r < 4; ++r) {
                    int bl = mt * 16 + q * 4 + r;
                    float rr = sigmoid_(accR[mt][i][r]);
                    float zz = sigmoid_(accZ[mt][i][r]);
                    float nn = tanh_(accXN[mt][i][r] + rr * accHN[mt][i][r]);
                    float hOld = bf2f(sX[bl * XSTRIDE + OBS_DIMM + u]);
                    float hN = (1.f - zz) * nn + zz * hOld;
                    sX[bl * XSTRIDE + OBS_DIMM + u] = f2bf(hN);
                    float sp = 0.69314718f * flog2(1.f + fexp2(1.44269504f * hN));
                    sM[bl * MSTRIDE + u] = f2bf(hN * tanh_(sp));
                }
            }
        __syncthreads();  // mish + h_new visible

        // ---- phase 4: out[b,t,:] = mish(h) @ W_out + b_out (only own chunk)
        if (w < 4 && t >= t0) {
            int mto = w >> 1, nto = w & 1;
            f32x4 acc = (f32x4){bOutV, bOutV, bOutV, bOutV};
#pragma unroll
            for (int ks = 0; ks < 8; ++ks) {
                bf16x8 a = *(const bf16x8*)(sM + (mto * 16 + c16) * MSTRIDE + ks * 32 + q * 8);
                acc = MFMA16(a, wo[ks], acc);
            }
            int col = nto * 16 + c16;
            if (col < LATT) {
#pragma unroll
                for (int r = 0; r < 4; ++r) {
                    int b = b0 + mto * 16 + q * 4 + r;
                    out[((size_t)b * TTIME + t) * LATT + col] = acc[r];
                }
            }
        }
    }

    // ---- h_final from the last chunk's blocks
    if (ch == 7) {
#pragma unroll
        for (int ii = 0; ii < 16; ++ii) {
            int v = tid * 16 + ii;
            int bl = v >> 8, u = v & 255;
            hfin[(size_t)(b0 + bl) * HIDD + u] = bf2f(sX[bl * XSTRIDE + OBS_DIMM + u]);
        }
    }
}

extern "C" void kernel_launch(void* const* d_in, const int* in_sizes, int n_in,
                              void* d_out, int out_size, void* d_ws, size_t ws_size,
                              hipStream_t stream) {
    const float* obs    = (const float*)d_in[0];
    const int*   isini  = (const int*)d_in[1];
    const float* hx     = (const float*)d_in[2];
    const float* W_in   = (const float*)d_in[3];
    const float* b_in   = (const float*)d_in[4];
    const float* W_ih   = (const float*)d_in[5];
    const float* b_ih   = (const float*)d_in[6];
    const float* W_hh   = (const float*)d_in[7];
    const float* b_hh   = (const float*)d_in[8];
    const float* W_out  = (const float*)d_in[9];
    const float* b_out  = (const float*)d_in[10];

    // workspace layout (needs ~610 KB): W' bf16 | W_out' bf16 | b_x f32
    unsigned short* wsW  = (unsigned short*)d_ws;
    unsigned short* wsWo = wsW + KDIM * NGATE;        // 294912 elems
    float*          wsBx = (float*)(wsWo + 256 * 32); // 8192 elems

    float* outp = (float*)d_out;
    float* hfin = outp + (size_t)BBATCH * TTIME * LATT;

    prep_kernel<<<1187, 256, 0, stream>>>(W_in, b_in, W_ih, b_ih, W_hh, W_out, wsW, wsWo, wsBx);
    gru_kernel<<<256, 512, 0, stream>>>(obs, isini, hx, b_hh, b_out, wsW, wsWo, wsBx, outp, hfin);
}